// Round 6
// baseline (539.759 us; speedup 1.0000x reference)
//
#include <hip/hip_runtime.h>

// IsolatedAttention: B=4, S=4096, D=1024, single head, fp32 in/out.
// All GEMMs in bf16 MFMA (16x16x32), fp32 accumulate.
// R5: algebraic elimination of K projection: T = X (Wk^T Wq)^T (562us).
// R6: 256x256 coarse 2-phase + swizzle; projections ~90us total (519us).
// R7: 4-phase 256^2: neutral on big GEMMs (1 blk/CU). (524us)
// R8: 256x128 3-buf big GEMMs: 179-180us each, 2 blk/CU -- best. (545 tot,
//     projections on wrong kernel)
// R9: XCD swizzle poisoned L3 reuse of the 128MB S panel: FETCH 152->640MB.
//     (578us) Lesson: L3-resident reuse beats XCD L2 affinity here.
// R10: swizzle reverted; VT-direct (M=1024,N=4096) projections on the
//     4-phase kernel cost ~100us vs 50 expected -- skinny-M orientation
//     re-reads X 4x and starves waves. (533us)
// R11: argmin recombination, no new schedules:
//     score/PV  = R8/R10 256x128 3-buf kernel (179us each, proven).
//     V-proj/T-proj = R6 coarse 256^2 3-buf 2-phase kernel, A=X
//     orientation (M=16384), explicit V transpose. Others ~135us.

typedef __bf16 bf16_t;
typedef __bf16 bf16x8 __attribute__((ext_vector_type(8)));
typedef float f32x4 __attribute__((ext_vector_type(4)));

typedef __attribute__((address_space(3))) void lds_void_t;
typedef __attribute__((address_space(1))) void gbl_void_t;

#define SEQ 4096
#define DM  1024

// ---------------- cast fp32 -> bf16 (8 elems/thread) ----------------
__global__ __launch_bounds__(256) void cast_f32_to_bf16(
    const float* __restrict__ in, bf16_t* __restrict__ out, int n8)
{
    int idx = blockIdx.x * 256 + threadIdx.x;
    if (idx >= n8) return;
    long i = (long)idx * 8;
    f32x4 a = *(const f32x4*)(in + i);
    f32x4 b = *(const f32x4*)(in + i + 4);
    bf16x8 o;
    o[0] = (bf16_t)a[0]; o[1] = (bf16_t)a[1]; o[2] = (bf16_t)a[2]; o[3] = (bf16_t)a[3];
    o[4] = (bf16_t)b[0]; o[5] = (bf16_t)b[1]; o[6] = (bf16_t)b[2]; o[7] = (bf16_t)b[3];
    *(bf16x8*)(out + i) = o;
}

// cast three 1024x1024 fp32 weights to bf16, z selects the source
__global__ __launch_bounds__(256) void cast3_w(
    const float* __restrict__ w0, const float* __restrict__ w1,
    const float* __restrict__ w2, bf16_t* __restrict__ out)
{
    const float* in = (blockIdx.z == 0) ? w0 : (blockIdx.z == 1) ? w1 : w2;
    long i = ((long)blockIdx.x * 256 + threadIdx.x) * 8;
    f32x4 a = *(const f32x4*)(in + i);
    f32x4 b = *(const f32x4*)(in + i + 4);
    bf16x8 o;
    o[0] = (bf16_t)a[0]; o[1] = (bf16_t)a[1]; o[2] = (bf16_t)a[2]; o[3] = (bf16_t)a[3];
    o[4] = (bf16_t)b[0]; o[5] = (bf16_t)b[1]; o[6] = (bf16_t)b[2]; o[7] = (bf16_t)b[3];
    *(bf16x8*)(out + (long)blockIdx.z * 1048576 + i) = o;
}

// ---------------- zero an fp32 buffer ----------------
__global__ __launch_bounds__(256) void zero_f32(float* __restrict__ p, int n)
{
    int idx = blockIdx.x * 256 + threadIdx.x;
    if (idx < n) p[idx] = 0.f;
}

// ------- bt-GEMM (128-tile, m97 structure) — kept for Mt + fallback -------
template <typename TOUT, int MODE>
__global__ __launch_bounds__(256, 4) void gemm_bt(
    const bf16_t* __restrict__ A, int lda, long sAz,
    const bf16_t* __restrict__ B, int ldb, long sBz,
    TOUT* __restrict__ C, int ldc, long sCz,
    int K, float scale, float* __restrict__ l, long sLz)
{
    __shared__ bf16_t As[128 * 32];
    __shared__ bf16_t Bs[128 * 32];

    A += (long)blockIdx.z * sAz;
    B += (long)blockIdx.z * sBz;
    C += (long)blockIdx.z * sCz;

    const int tid  = threadIdx.x;
    const int wave = tid >> 6;
    const int lane = tid & 63;
    const int m0 = blockIdx.x * 128;
    const int n0 = blockIdx.y * 128;
    const int wm = (wave >> 1) * 64;
    const int wn = (wave & 1) * 64;
    const int mrow = lane & 15;
    const int koff = (lane >> 4) * 8;

    f32x4 acc[4][4];
#pragma unroll
    for (int i = 0; i < 4; ++i)
#pragma unroll
        for (int j = 0; j < 4; ++j)
            acc[i][j] = (f32x4){0.f, 0.f, 0.f, 0.f};

    const int c0 = wave * 2;

    for (int k0 = 0; k0 < K; k0 += 32) {
#pragma unroll
        for (int t = 0; t < 2; ++t) {
            const int chunk = c0 + t;
            const int flat  = chunk * 64 + lane;
            const int row   = flat >> 2;
            const int kp    = (flat & 3) * 8;
            const bf16_t* ga = A + (long)(m0 + row) * lda + (k0 + kp);
            const bf16_t* gb = B + (long)(n0 + row) * ldb + (k0 + kp);
            __builtin_amdgcn_global_load_lds((const gbl_void_t*)ga,
                                             (lds_void_t*)(As + chunk * 512), 16, 0, 0);
            __builtin_amdgcn_global_load_lds((const gbl_void_t*)gb,
                                             (lds_void_t*)(Bs + chunk * 512), 16, 0, 0);
        }
        __syncthreads();

        bf16x8 af[4], bfr[4];
#pragma unroll
        for (int i = 0; i < 4; ++i)
            af[i] = *(const bf16x8*)(As + (wm + i * 16 + mrow) * 32 + koff);
#pragma unroll
        for (int j = 0; j < 4; ++j)
            bfr[j] = *(const bf16x8*)(Bs + (wn + j * 16 + mrow) * 32 + koff);
#pragma unroll
        for (int i = 0; i < 4; ++i)
#pragma unroll
            for (int j = 0; j < 4; ++j)
                acc[i][j] = __builtin_amdgcn_mfma_f32_16x16x32_bf16(af[i], bfr[j], acc[i][j], 0, 0, 0);
        __syncthreads();
    }

    const int col = lane & 15;
    const int r0  = (lane >> 4) * 4;

    if (MODE == 1) {
#pragma unroll
        for (int i = 0; i < 4; ++i)
#pragma unroll
            for (int r = 0; r < 4; ++r) {
                float s = 0.f;
#pragma unroll
                for (int j = 0; j < 4; ++j) {
                    float e = __expf(acc[i][j][r] * scale);
                    acc[i][j][r] = e;
                    s += e;
                }
                s += __shfl_xor(s, 1);
                s += __shfl_xor(s, 2);
                s += __shfl_xor(s, 4);
                s += __shfl_xor(s, 8);
                if (col == 0)
                    atomicAdd(&l[(long)blockIdx.z * sLz + m0 + wm + i * 16 + r0 + r], s);
            }
#pragma unroll
        for (int i = 0; i < 4; ++i)
#pragma unroll
            for (int j = 0; j < 4; ++j)
#pragma unroll
                for (int r = 0; r < 4; ++r)
                    C[(long)(m0 + wm + i * 16 + r0 + r) * ldc + (n0 + wn + j * 16 + col)] =
                        (TOUT)acc[i][j][r];
    } else if (MODE == 2) {
        float inv[4][4];
#pragma unroll
        for (int i = 0; i < 4; ++i)
#pragma unroll
            for (int r = 0; r < 4; ++r)
                inv[i][r] = scale / l[(long)blockIdx.z * sLz + m0 + wm + i * 16 + r0 + r];
#pragma unroll
        for (int i = 0; i < 4; ++i)
#pragma unroll
            for (int j = 0; j < 4; ++j)
#pragma unroll
                for (int r = 0; r < 4; ++r)
                    C[(long)(m0 + wm + i * 16 + r0 + r) * ldc + (n0 + wn + j * 16 + col)] =
                        (TOUT)(acc[i][j][r] * inv[i][r]);
    } else {
#pragma unroll
        for (int i = 0; i < 4; ++i)
#pragma unroll
            for (int j = 0; j < 4; ++j)
#pragma unroll
                for (int r = 0; r < 4; ++r)
                    C[(long)(m0 + wm + i * 16 + r0 + r) * ldc + (n0 + wn + j * 16 + col)] =
                        (TOUT)(acc[i][j][r] * scale);
    }
}

// ===== gemm_proj: R6 coarse 256x256, BK=32, triple-buffered 96KiB LDS =====
// 2-phase per K-tile, counted vmcnt(4) (tile t+2 in flight across the
// barrier), st_16x32-class swizzle: linear global_load_lds dest +
// inverse-swizzled global src (lanes>=32 flip k by 16) + swizzled ds_read.
// Proven in R6 (conflicts 0, projections ~40-45us each). bf16 out, MODE0.
__global__ __launch_bounds__(512, 2) void gemm_proj(
    const bf16_t* __restrict__ A, int lda, long sAz,
    const bf16_t* __restrict__ B, int ldb, long sBz,
    bf16_t* __restrict__ C, int ldc, long sCz,
    int K, float scale)
{
    // [0,48K): A bufs x3 (16 KiB each)   [48K,96K): B bufs x3
    __shared__ __align__(1024) char smem[98304];

    A += (long)blockIdx.z * sAz;
    B += (long)blockIdx.z * sBz;
    C += (long)blockIdx.z * sCz;

    const int tid  = threadIdx.x;
    const int wave = tid >> 6;        // 0..7
    const int lane = tid & 63;
    const int m0 = blockIdx.x * 256;
    const int n0 = blockIdx.y * 256;
    const int wm = (wave >> 2) * 128; // 2 row-groups of 128
    const int wn = (wave & 3) * 64;   // 4 col-groups of 64

    // staging: linear LDS dest, pre-swizzled per-lane global source
    const int srow = wave * 16 + (lane >> 2);                       // 0..127
    const int skk  = ((lane & 3) * 8) ^ ((lane & 32) ? 16 : 0);     // elems
    const bf16_t* gA0 = A + (long)(m0 + srow) * lda + skk;
    const bf16_t* gA1 = A + (long)(m0 + srow + 128) * lda + skk;
    const bf16_t* gB0 = B + (long)(n0 + srow) * ldb + skk;
    const bf16_t* gB1 = B + (long)(n0 + srow + 128) * ldb + skk;
    char* ldsA = smem + wave * 1024;          // + buf*16384 (+8192 hi half)
    char* ldsB = smem + 49152 + wave * 1024;

    auto stage_A = [&](int kt, int d) {
        const int k0 = kt << 5;
        __builtin_amdgcn_global_load_lds((const gbl_void_t*)(gA0 + k0),
                                         (lds_void_t*)(ldsA + d * 16384), 16, 0, 0);
        __builtin_amdgcn_global_load_lds((const gbl_void_t*)(gA1 + k0),
                                         (lds_void_t*)(ldsA + d * 16384 + 8192), 16, 0, 0);
    };
    auto stage_B = [&](int kt, int d) {
        const int k0 = kt << 5;
        __builtin_amdgcn_global_load_lds((const gbl_void_t*)(gB0 + k0),
                                         (lds_void_t*)(ldsB + d * 16384), 16, 0, 0);
        __builtin_amdgcn_global_load_lds((const gbl_void_t*)(gB1 + k0),
                                         (lds_void_t*)(ldsB + d * 16384 + 8192), 16, 0, 0);
    };

    // ds_read: swizzled k-slot
    const int kswz = ((lane >> 4) * 16) ^ ((lane & 8) ? 32 : 0);
    const int aoff = (wm + (lane & 15)) * 64 + kswz;
    const int boff = (wn + (lane & 15)) * 64 + kswz;

    f32x4 acc[8][4];
#pragma unroll
    for (int i = 0; i < 8; ++i)
#pragma unroll
        for (int j = 0; j < 4; ++j)
            acc[i][j] = (f32x4){0.f, 0.f, 0.f, 0.f};

    const int NT = K >> 5;

    stage_A(0, 0); stage_B(0, 0);
    if (NT > 1) {
        stage_A(1, 1); stage_B(1, 1);
        asm volatile("s_waitcnt vmcnt(4)" ::: "memory");
    } else {
        asm volatile("s_waitcnt vmcnt(0)" ::: "memory");
    }
    __builtin_amdgcn_s_barrier();

    int cur = 0, nxt = 2;
    for (int t = 0; t < NT; ++t) {
        const char* pa = smem + cur * 16384 + aoff;
        const char* pb = smem + 49152 + cur * 16384 + boff;

        // phase 1: B frags + A rows [wm, wm+64), stage A(t+2)
        bf16x8 bfr[4], af[4];
#pragma unroll
        for (int j = 0; j < 4; ++j) bfr[j] = *(const bf16x8*)(pb + j * 1024);
#pragma unroll
        for (int i = 0; i < 4; ++i) af[i] = *(const bf16x8*)(pa + i * 1024);
        if (t + 2 < NT) stage_A(t + 2, nxt);
        __builtin_amdgcn_s_setprio(1);
#pragma unroll
        for (int i = 0; i < 4; ++i)
#pragma unroll
            for (int j = 0; j < 4; ++j)
                acc[i][j] = __builtin_amdgcn_mfma_f32_16x16x32_bf16(af[i], bfr[j], acc[i][j], 0, 0, 0);
        __builtin_amdgcn_s_setprio(0);

        // phase 2: A rows [wm+64, wm+128), stage B(t+2)
        bf16x8 af2[4];
#pragma unroll
        for (int i = 0; i < 4; ++i) af2[i] = *(const bf16x8*)(pa + 4096 + i * 1024);
        if (t + 2 < NT) stage_B(t + 2, nxt);
        __builtin_amdgcn_s_setprio(1);
#pragma unroll
        for (int i = 0; i < 4; ++i)
#pragma unroll
            for (int j = 0; j < 4; ++j)
                acc[4 + i][j] = __builtin_amdgcn_mfma_f32_16x16x32_bf16(af2[i], bfr[j], acc[4 + i][j], 0, 0, 0);
        __builtin_amdgcn_s_setprio(0);

        // boundary: counted vmcnt (tile t+1 landed, t+2 in flight)
        __builtin_amdgcn_sched_barrier(0);
        if (t + 2 < NT)
            asm volatile("s_waitcnt vmcnt(4) lgkmcnt(0)" ::: "memory");
        else if (t + 1 < NT)
            asm volatile("s_waitcnt vmcnt(0) lgkmcnt(0)" ::: "memory");
        else
            asm volatile("s_waitcnt lgkmcnt(0)" ::: "memory");
        __builtin_amdgcn_s_barrier();
        cur = (cur == 2) ? 0 : cur + 1;
        nxt = (nxt == 2) ? 0 : nxt + 1;
    }

    const int col = lane & 15;
    const int r0  = (lane >> 4) * 4;
#pragma unroll
    for (int i = 0; i < 8; ++i)
#pragma unroll
        for (int j = 0; j < 4; ++j)
#pragma unroll
            for (int r = 0; r < 4; ++r)
                C[(long)(m0 + wm + i * 16 + r0 + r) * ldc + (n0 + wn + j * 16 + col)] =
                    (bf16_t)(acc[i][j][r] * scale);
}

// ===== score/PV: 256x128 tile, BK=32, 8 waves, 3-buffered 72KiB LDS =====
// 2 blocks/CU, counted vmcnt(3), one barrier per K-tile, 2-way-max LDS
// swizzle (slot ^= (row>>1)&3 both-sides). Natural block order.
template <typename TOUT, int MODE, int LDA, int LDB, int LDC>
__global__ __launch_bounds__(512, 4) void gemm_bt256(
    const bf16_t* __restrict__ A, long sAz,
    const bf16_t* __restrict__ B, long sBz,
    TOUT* __restrict__ C, long sCz,
    int K, float scale, float* __restrict__ l, long sLz)
{
    __shared__ __align__(1024) char smem[73728];

    A += (long)blockIdx.z * sAz;
    B += (long)blockIdx.z * sBz;
    C += (long)blockIdx.z * sCz;

    const int m0 = blockIdx.x * 256;
    const int n0 = blockIdx.y * 128;

    const int tid  = threadIdx.x;
    const int wave = tid >> 6;        // 0..7
    const int lane = tid & 63;
    const int wm = (wave >> 2) * 128; // wave's 128-row slice of A-tile
    const int wn = (wave & 3) * 32;   // wave's 32-row slice of B-tile

    // staging source (per-lane, inverse-swizzled k slot)
    const int srow = wave * 16 + (lane >> 2);
    const int ksrc = (((lane & 3) ^ ((lane >> 3) & 3)) << 3);  // elems
    const bf16_t* pa0 = A + (long)(m0 + srow) * LDA + ksrc;
    const bf16_t* pa1 = pa0 + (long)128 * LDA;
    const bf16_t* pb0 = B + (long)(n0 + srow) * LDB + ksrc;
    const int ldsw = wave * 1024;

    // ds_read offsets (swizzled slot)
    const int kterm = (((lane >> 4) ^ ((lane >> 1) & 3)) << 4);  // bytes
    const int aoff = (wm + (lane & 15)) * 64 + kterm;
    const int boff = (wn + (lane & 15)) * 64 + kterm;

    f32x4 acc[8][2];
#pragma unroll
    for (int i = 0; i < 8; ++i)
#pragma unroll
        for (int j = 0; j < 2; ++j)
            acc[i][j] = (f32x4){0.f, 0.f, 0.f, 0.f};

    const int NT = K >> 5;

#define STAGE_A2(buf)                                                          \
    do {                                                                       \
        __builtin_amdgcn_global_load_lds((const gbl_void_t*)pa0,               \
            (lds_void_t*)(smem + (buf)*16384 + ldsw), 16, 0, 0);               \
        __builtin_amdgcn_global_load_lds((const gbl_void_t*)pa1,               \
            (lds_void_t*)(smem + (buf)*16384 + 8192 + ldsw), 16, 0, 0);        \
    } while (0)
#define STAGE_B1(buf)                                                          \
    __builtin_amdgcn_global_load_lds((const gbl_void_t*)pb0,                   \
        (lds_void_t*)(smem + 49152 + (buf)*8192 + ldsw), 16, 0, 0)

    // prologue: stage tiles 0 and 1; wait tile 0 (leave tile 1 in flight)
    STAGE_A2(0); STAGE_B1(0); pa0 += 32; pa1 += 32; pb0 += 32;
    if (NT > 1) {
        STAGE_A2(1); STAGE_B1(1); pa0 += 32; pa1 += 32; pb0 += 32;
        asm volatile("s_waitcnt vmcnt(3)" ::: "memory");
    } else {
        asm volatile("s_waitcnt vmcnt(0)" ::: "memory");
    }
    __builtin_amdgcn_sched_barrier(0);
    __builtin_amdgcn_s_barrier();

    int cur = 0, sb = 2;
    for (int t = 0; t < NT; ++t) {
        const char* Ab = smem + cur * 16384;
        const char* Bb = smem + 49152 + cur * 8192;
        const bool more = (t + 2 < NT);

        bf16x8 bfr[2], af[4];
#pragma unroll
        for (int j = 0; j < 2; ++j) bfr[j] = *(const bf16x8*)(Bb + boff + j * 1024);
#pragma unroll
        for (int i = 0; i < 4; ++i) af[i] = *(const bf16x8*)(Ab + aoff + i * 1024);
        if (more) STAGE_A2(sb);
        asm volatile("s_waitcnt lgkmcnt(0)" ::: "memory");
        __builtin_amdgcn_sched_barrier(0);
        __builtin_amdgcn_s_setprio(1);
#pragma unroll
        for (int i = 0; i < 4; ++i)
#pragma unroll
            for (int j = 0; j < 2; ++j)
                acc[i][j] = __builtin_amdgcn_mfma_f32_16x16x32_bf16(af[i], bfr[j], acc[i][j], 0, 0, 0);
        __builtin_amdgcn_s_setprio(0);

#pragma unroll
        for (int i = 0; i < 4; ++i) af[i] = *(const bf16x8*)(Ab + aoff + 4096 + i * 1024);
        if (more) STAGE_B1(sb);
        asm volatile("s_waitcnt lgkmcnt(0)" ::: "memory");
        __builtin_amdgcn_sched_barrier(0);
        __builtin_amdgcn_s_setprio(1);
#pragma unroll
        for (int i = 0; i < 4; ++i)
#pragma unroll
            for (int j = 0; j < 2; ++j)
                acc[4 + i][j] = __builtin_amdgcn_mfma_f32_16x16x32_bf16(af[i], bfr[j], acc[4 + i][j], 0, 0, 0);
        __builtin_amdgcn_s_setprio(0);

        // boundary: retire tile t+1's loads; keep tile t+2's in flight
        if (more) {
            asm volatile("s_waitcnt vmcnt(3)" ::: "memory");
            pa0 += 32; pa1 += 32; pb0 += 32;
        } else if (t + 1 < NT) {
            asm volatile("s_waitcnt vmcnt(0)" ::: "memory");
        }
        __builtin_amdgcn_sched_barrier(0);
        __builtin_amdgcn_s_barrier();
        cur = (cur == 2) ? 0 : cur + 1;
        sb  = (sb == 2) ? 0 : sb + 1;
    }
#undef STAGE_A2
#undef STAGE_B1

    // ---- epilogue: C/D layout col = lane&15, row = (lane>>4)*4 + reg ----
    const int col = lane & 15;
    const int r0  = (lane >> 4) * 4;

    if (MODE == 1) {
#pragma unroll
        for (int i = 0; i < 8; ++i)
#pragma unroll
            for (int r = 0; r < 4; ++r) {
                float s = 0.f;
#pragma unroll
                for (int j = 0; j < 2; ++j) {
                    float e = __expf(acc[i][j][r] * scale);
                    acc[i][j][r] = e;
                    s += e;
                }
                s += __shfl_xor(s, 1);
                s += __shfl_xor(s, 2);
                s += __shfl_xor(s, 4);
                s += __shfl_xor(s, 8);
                if (col == 0)
                    atomicAdd(&l[(long)blockIdx.z * sLz + m0 + wm + i * 16 + r0 + r], s);
            }
#pragma unroll
        for (int i = 0; i < 8; ++i)
#pragma unroll
            for (int j = 0; j < 2; ++j)
#pragma unroll
                for (int r = 0; r < 4; ++r)
                    C[(long)(m0 + wm + i * 16 + r0 + r) * LDC + (n0 + wn + j * 16 + col)] =
                        (TOUT)acc[i][j][r];
    } else if (MODE == 2) {
        float inv[8][4];
#pragma unroll
        for (int i = 0; i < 8; ++i)
#pragma unroll
            for (int r = 0; r < 4; ++r)
                inv[i][r] = scale / l[(long)blockIdx.z * sLz + m0 + wm + i * 16 + r0 + r];
#pragma unroll
        for (int i = 0; i < 8; ++i)
#pragma unroll
            for (int j = 0; j < 2; ++j)
#pragma unroll
                for (int r = 0; r < 4; ++r)
                    C[(long)(m0 + wm + i * 16 + r0 + r) * LDC + (n0 + wn + j * 16 + col)] =
                        (TOUT)(acc[i][j][r] * inv[i][r]);
    } else {
#pragma unroll
        for (int i = 0; i < 8; ++i)
#pragma unroll
            for (int j = 0; j < 2; ++j)
#pragma unroll
                for (int r = 0; r < 4; ++r)
                    C[(long)(m0 + wm + i * 16 + r0 + r) * LDC + (n0 + wn + j * 16 + col)] =
                        (TOUT)(acc[i][j][r] * scale);
    }
}

// ---------------- row softmax (fallback path only) ----------------
__device__ __forceinline__ float waveMax(float v)
{
#pragma unroll
    for (int o = 32; o > 0; o >>= 1) v = fmaxf(v, __shfl_xor(v, o));
    return v;
}
__device__ __forceinline__ float waveSum(float v)
{
#pragma unroll
    for (int o = 32; o > 0; o >>= 1) v += __shfl_xor(v, o);
    return v;
}

__global__ __launch_bounds__(256) void softmax_rows(bf16_t* __restrict__ S)
{
    const long row = blockIdx.x;
    bf16_t* p = S + row * SEQ;
    const int tid = threadIdx.x;

    float v[16];
    bf16x8 a0 = *(const bf16x8*)(p + tid * 16);
    bf16x8 a1 = *(const bf16x8*)(p + tid * 16 + 8);
#pragma unroll
    for (int i = 0; i < 8; ++i) { v[i] = (float)a0[i]; v[8 + i] = (float)a1[i]; }

    float m = -1e30f;
#pragma unroll
    for (int i = 0; i < 16; ++i) m = fmaxf(m, v[i]);

    __shared__ float redm[4];
    __shared__ float reds[4];
    m = waveMax(m);
    if ((tid & 63) == 0) redm[tid >> 6] = m;
    __syncthreads();
    m = fmaxf(fmaxf(redm[0], redm[1]), fmaxf(redm[2], redm[3]));

    float s = 0.f;
#pragma unroll
    for (int i = 0; i < 16; ++i) { v[i] = __expf(v[i] - m); s += v[i]; }
    s = waveSum(s);
    if ((tid & 63) == 0) reds[tid >> 6] = s;
    __syncthreads();
    s = reds[0] + reds[1] + reds[2] + reds[3];
    const float inv = 1.0f / s;

    bf16x8 o0, o1;
#pragma unroll
    for (int i = 0; i < 8; ++i) {
        o0[i] = (bf16_t)(v[i] * inv);
        o1[i] = (bf16_t)(v[8 + i] * inv);
    }
    *(bf16x8*)(p + tid * 16)     = o0;
    *(bf16x8*)(p + tid * 16 + 8) = o1;
}

// ------- bf16 tile transpose (z-batched): out[z][x][y] = in[z][y][x] -------
__global__ __launch_bounds__(256) void transpose_bf16(
    const bf16_t* __restrict__ in, int ldin, long sInZ,
    bf16_t* __restrict__ out, int ldout, long sOutZ)
{
    in  += (long)blockIdx.z * sInZ;
    out += (long)blockIdx.z * sOutZ;
    __shared__ bf16_t t[32][33];
    const int tx = threadIdx.x;  // 0..31
    const int ty = threadIdx.y;  // 0..7
    const int x  = blockIdx.x * 32 + tx;
    const int y0 = blockIdx.y * 32;
#pragma unroll
    for (int i = 0; i < 4; ++i)
        t[ty + i * 8][tx] = in[(long)(y0 + ty + i * 8) * ldin + x];
    __syncthreads();
    const int xo = blockIdx.x * 32;
#pragma unroll
    for (int i = 0; i < 4; ++i)
        out[(long)(xo + ty + i * 8) * ldout + y0 + tx] = t[tx][ty + i * 8];
}

// ---------------- launcher ----------------
extern "C" void kernel_launch(void* const* d_in, const int* in_sizes, int n_in,
                              void* d_out, int out_size, void* d_ws, size_t ws_size,
                              hipStream_t stream)
{
    const float* X  = (const float*)d_in[0];  // (4,4096,1024)
    const float* Wq = (const float*)d_in[1];  // (1024,1024)
    const float* Wk = (const float*)d_in[2];
    const float* Wv = (const float*)d_in[3];
    float* out = (float*)d_out;               // (4,4096,1024) fp32
    char* ws = (char*)d_ws;

    if (ws_size >= (256ull << 20)) {
        // ===== batched fused path (<=237 MiB used) =====
        // [0,32M)     Xbf (alive until score GEMM)
        // [32,64M)    Vbf, then reused as Tbuf (V dead after transpose)
        // [64,96M)    VT x4 (bf16 1024x4096 each)
        // [96,224M)   S0..S3 (bf16 4096x4096 each, = exp(scores))
        // [224,230M)  Wall = bf16 [Wq;Wk;Wv]
        // [230,232M)  WqT   [232,234M) WkT   [234,236M) Mt = Wk^T Wq
        // [236M,+64K) l (fp32 16384)
        bf16_t* Xbf  = (bf16_t*)ws;
        bf16_t* Vbf  = (bf16_t*)(ws + (32l << 20));
        bf16_t* Tbuf = (bf16_t*)(ws + (32l << 20));   // reuses Vbf after transV
        bf16_t* VT   = (bf16_t*)(ws + (64l << 20));
        bf16_t* Sbuf = (bf16_t*)(ws + (96l << 20));
        bf16_t* Wall = (bf16_t*)(ws + (224l << 20));
        bf16_t* WqT  = (bf16_t*)(ws + (230l << 20));
        bf16_t* WkT  = (bf16_t*)(ws + (232l << 20));
        bf16_t* Mt   = (bf16_t*)(ws + (234l << 20));
        float*  lbuf = (float*)(ws + (236l << 20));

        cast_f32_to_bf16<<<(16777216 / 8) / 256, 256, 0, stream>>>(X, Xbf, 16777216 / 8);
        cast3_w<<<dim3(512, 1, 3), 256, 0, stream>>>(Wq, Wk, Wv, Wall);

        transpose_bf16<<<dim3(32, 32, 2), dim3(32, 8), 0, stream>>>(
            Wall, DM, 1048576, WqT, DM, 1048576);

        // Mt = Wk^T Wq, 1024x1024 (small; 128-tile path)
        gemm_bt<bf16_t, 0><<<dim3(8, 8, 1), 256, 0, stream>>>(
            WkT, DM, 0l, WqT, DM, 0l, Mt, DM, 0l, DM, 1.0f, nullptr, 0l);

        // V = X @ Wv^T : M=16384, N=1024, K=1024 (A=X orientation, R6-proven)
        gemm_proj<<<dim3(64, 4, 1), 512, 0, stream>>>(
            Xbf, DM, 0l, Wall + 2097152, DM, 0l, Vbf, DM, 0l, DM, 1.0f);

        // VT[b][d][s] = V[b][s][d]
        transpose_bf16<<<dim3(DM / 32, SEQ / 32, 4), dim3(32, 8), 0, stream>>>(
            Vbf, DM, (long)SEQ * DM, VT, SEQ, (long)DM * SEQ);

        // T = X @ Mt^T : replaces BOTH Q and K projections (into dead Vbf)
        gemm_proj<<<dim3(64, 4, 1), 512, 0, stream>>>(
            Xbf, DM, 0l, Mt, DM, 0l, Tbuf, DM, 0l, DM, 1.0f);

        zero_f32<<<64, 256, 0, stream>>>(lbuf, 4 * SEQ);

        // P[b] = exp(T[b] X[b]^T / 32), l[b][row] += row sums
        gemm_bt256<bf16_t, 1, DM, DM, SEQ><<<dim3(16, 32, 4), 512, 0, stream>>>(
            Tbuf, (long)SEQ * DM,
            Xbf, (long)SEQ * DM,
            Sbuf, (long)SEQ * SEQ, DM, 0.03125f, lbuf, SEQ);

        // O[b] = (P[b] @ V[b]) / l : M=4096, N=1024, K=4096
        gemm_bt256<float, 2, SEQ, SEQ, DM><<<dim3(16, 8, 4), 512, 0, stream>>>(
            Sbuf, (long)SEQ * SEQ,
            VT, (long)DM * SEQ,
            out, (long)SEQ * DM, SEQ, 1.0f, lbuf, SEQ);
    } else {
        // ===== fallback: per-batch path (<=145 MiB ws, proven) =====
        bf16_t* Sbuf = (bf16_t*)ws;
        bf16_t* Xbf  = (bf16_t*)ws;
        bf16_t* Wall = (bf16_t*)(ws + (33l << 20));
        bf16_t* QKV  = (bf16_t*)(ws + (40l << 20));
        bf16_t* VT   = (bf16_t*)(ws + (137l << 20));

        cast_f32_to_bf16<<<(16777216 / 8) / 256, 256, 0, stream>>>(X, Xbf, 16777216 / 8);
        cast3_w<<<dim3(512, 1, 3), 256, 0, stream>>>(Wq, Wk, Wv, Wall);

        gemm_bt<bf16_t, 0><<<dim3(128, 24, 1), 256, 0, stream>>>(
            Xbf, DM, 0l, Wall, DM, 0l, QKV, 3072, 0l, DM, 1.0f, nullptr, 0l);

        for (int b = 0; b < 4; ++b) {
            const bf16_t* Qb = QKV + (long)b * SEQ * 3072;
            gemm_bt<bf16_t, 0><<<dim3(32, 32, 1), 256, 0, stream>>>(
                Qb, 3072, 0l, Qb + 1024, 3072, 0l, Sbuf, SEQ, 0l, DM, 0.03125f, nullptr, 0l);
            softmax_rows<<<SEQ, 256, 0, stream>>>(Sbuf);
            transpose_bf16<<<dim3(DM / 32, SEQ / 32, 1), dim3(32, 8), 0, stream>>>(
                Qb + 2048, 3072, 0l, VT, SEQ, 0l);
            gemm_bt<float, 0><<<dim3(32, 8, 1), 256, 0, stream>>>(
                Sbuf, SEQ, 0l, VT, SEQ, 0l, out + (long)b * SEQ * DM, DM, 0l, SEQ, 1.0f, nullptr, 0l);
        }
    }
}

// Round 7
// 510.299 us; speedup vs baseline: 1.0577x; 1.0577x over previous
//
#include <hip/hip_runtime.h>

// IsolatedAttention: B=4, S=4096, D=1024, single head, fp32 in/out.
// All GEMMs in bf16 MFMA (16x16x32), fp32 accumulate.
// R5: algebraic elimination of K projection: T = X (Wk^T Wq)^T (562us).
// R6: 256^2 coarse 2-phase 3-buf everywhere (519us -- best so far).
// R7: 4-phase 256^2: neutral (524us). R8: 256x128 3-buf score/PV (545;
//     projections on wrong kernel). R9: XCD swizzle poisoned L3 (578).
// R10: VT-direct projections slow (533). R11: score+PV on 256x128 +
//     R6 projections = 539.8: score improved (177 vs 192) but PV
//     REGRESSED ~40us on 256x128 (BN=128 doubles S re-reads for the
//     long-K N=1024 GEMM). Lesson: score and PV want different tiles.
// R12: per-stage argmin with per-stage kernels:
//     score (K=1024,N=4096): 256x128/BK32/3-buf/counted-vmcnt(3) kernel.
//     PV (K=4096,N=1024) + V-proj + T-proj: R6's 256^2/BK32/3-buf/
//     2-phase/counted-vmcnt(4) kernel (gemm_big256, runtime ld, MODE tpl).

typedef __bf16 bf16_t;
typedef __bf16 bf16x8 __attribute__((ext_vector_type(8)));
typedef float f32x4 __attribute__((ext_vector_type(4)));

typedef __attribute__((address_space(3))) void lds_void_t;
typedef __attribute__((address_space(1))) void gbl_void_t;

#define SEQ 4096
#define DM  1024

// ---------------- cast fp32 -> bf16 (8 elems/thread) ----------------
__global__ __launch_bounds__(256) void cast_f32_to_bf16(
    const float* __restrict__ in, bf16_t* __restrict__ out, int n8)
{
    int idx = blockIdx.x * 256 + threadIdx.x;
    if (idx >= n8) return;
    long i = (long)idx * 8;
    f32x4 a = *(const f32x4*)(in + i);
    f32x4 b = *(const f32x4*)(in + i + 4);
    bf16x8 o;
    o[0] = (bf16_t)a[0]; o[1] = (bf16_t)a[1]; o[2] = (bf16_t)a[2]; o[3] = (bf16_t)a[3];
    o[4] = (bf16_t)b[0]; o[5] = (bf16_t)b[1]; o[6] = (bf16_t)b[2]; o[7] = (bf16_t)b[3];
    *(bf16x8*)(out + i) = o;
}

// cast three 1024x1024 fp32 weights to bf16, z selects the source
__global__ __launch_bounds__(256) void cast3_w(
    const float* __restrict__ w0, const float* __restrict__ w1,
    const float* __restrict__ w2, bf16_t* __restrict__ out)
{
    const float* in = (blockIdx.z == 0) ? w0 : (blockIdx.z == 1) ? w1 : w2;
    long i = ((long)blockIdx.x * 256 + threadIdx.x) * 8;
    f32x4 a = *(const f32x4*)(in + i);
    f32x4 b = *(const f32x4*)(in + i + 4);
    bf16x8 o;
    o[0] = (bf16_t)a[0]; o[1] = (bf16_t)a[1]; o[2] = (bf16_t)a[2]; o[3] = (bf16_t)a[3];
    o[4] = (bf16_t)b[0]; o[5] = (bf16_t)b[1]; o[6] = (bf16_t)b[2]; o[7] = (bf16_t)b[3];
    *(bf16x8*)(out + (long)blockIdx.z * 1048576 + i) = o;
}

// ---------------- zero an fp32 buffer ----------------
__global__ __launch_bounds__(256) void zero_f32(float* __restrict__ p, int n)
{
    int idx = blockIdx.x * 256 + threadIdx.x;
    if (idx < n) p[idx] = 0.f;
}

// ------- bt-GEMM (128-tile, m97 structure) — kept for Mt + fallback -------
template <typename TOUT, int MODE>
__global__ __launch_bounds__(256, 4) void gemm_bt(
    const bf16_t* __restrict__ A, int lda, long sAz,
    const bf16_t* __restrict__ B, int ldb, long sBz,
    TOUT* __restrict__ C, int ldc, long sCz,
    int K, float scale, float* __restrict__ l, long sLz)
{
    __shared__ bf16_t As[128 * 32];
    __shared__ bf16_t Bs[128 * 32];

    A += (long)blockIdx.z * sAz;
    B += (long)blockIdx.z * sBz;
    C += (long)blockIdx.z * sCz;

    const int tid  = threadIdx.x;
    const int wave = tid >> 6;
    const int lane = tid & 63;
    const int m0 = blockIdx.x * 128;
    const int n0 = blockIdx.y * 128;
    const int wm = (wave >> 1) * 64;
    const int wn = (wave & 1) * 64;
    const int mrow = lane & 15;
    const int koff = (lane >> 4) * 8;

    f32x4 acc[4][4];
#pragma unroll
    for (int i = 0; i < 4; ++i)
#pragma unroll
        for (int j = 0; j < 4; ++j)
            acc[i][j] = (f32x4){0.f, 0.f, 0.f, 0.f};

    const int c0 = wave * 2;

    for (int k0 = 0; k0 < K; k0 += 32) {
#pragma unroll
        for (int t = 0; t < 2; ++t) {
            const int chunk = c0 + t;
            const int flat  = chunk * 64 + lane;
            const int row   = flat >> 2;
            const int kp    = (flat & 3) * 8;
            const bf16_t* ga = A + (long)(m0 + row) * lda + (k0 + kp);
            const bf16_t* gb = B + (long)(n0 + row) * ldb + (k0 + kp);
            __builtin_amdgcn_global_load_lds((const gbl_void_t*)ga,
                                             (lds_void_t*)(As + chunk * 512), 16, 0, 0);
            __builtin_amdgcn_global_load_lds((const gbl_void_t*)gb,
                                             (lds_void_t*)(Bs + chunk * 512), 16, 0, 0);
        }
        __syncthreads();

        bf16x8 af[4], bfr[4];
#pragma unroll
        for (int i = 0; i < 4; ++i)
            af[i] = *(const bf16x8*)(As + (wm + i * 16 + mrow) * 32 + koff);
#pragma unroll
        for (int j = 0; j < 4; ++j)
            bfr[j] = *(const bf16x8*)(Bs + (wn + j * 16 + mrow) * 32 + koff);
#pragma unroll
        for (int i = 0; i < 4; ++i)
#pragma unroll
            for (int j = 0; j < 4; ++j)
                acc[i][j] = __builtin_amdgcn_mfma_f32_16x16x32_bf16(af[i], bfr[j], acc[i][j], 0, 0, 0);
        __syncthreads();
    }

    const int col = lane & 15;
    const int r0  = (lane >> 4) * 4;

    if (MODE == 1) {
#pragma unroll
        for (int i = 0; i < 4; ++i)
#pragma unroll
            for (int r = 0; r < 4; ++r) {
                float s = 0.f;
#pragma unroll
                for (int j = 0; j < 4; ++j) {
                    float e = __expf(acc[i][j][r] * scale);
                    acc[i][j][r] = e;
                    s += e;
                }
                s += __shfl_xor(s, 1);
                s += __shfl_xor(s, 2);
                s += __shfl_xor(s, 4);
                s += __shfl_xor(s, 8);
                if (col == 0)
                    atomicAdd(&l[(long)blockIdx.z * sLz + m0 + wm + i * 16 + r0 + r], s);
            }
#pragma unroll
        for (int i = 0; i < 4; ++i)
#pragma unroll
            for (int j = 0; j < 4; ++j)
#pragma unroll
                for (int r = 0; r < 4; ++r)
                    C[(long)(m0 + wm + i * 16 + r0 + r) * ldc + (n0 + wn + j * 16 + col)] =
                        (TOUT)acc[i][j][r];
    } else if (MODE == 2) {
        float inv[4][4];
#pragma unroll
        for (int i = 0; i < 4; ++i)
#pragma unroll
            for (int r = 0; r < 4; ++r)
                inv[i][r] = scale / l[(long)blockIdx.z * sLz + m0 + wm + i * 16 + r0 + r];
#pragma unroll
        for (int i = 0; i < 4; ++i)
#pragma unroll
            for (int j = 0; j < 4; ++j)
#pragma unroll
                for (int r = 0; r < 4; ++r)
                    C[(long)(m0 + wm + i * 16 + r0 + r) * ldc + (n0 + wn + j * 16 + col)] =
                        (TOUT)(acc[i][j][r] * inv[i][r]);
    } else {
#pragma unroll
        for (int i = 0; i < 4; ++i)
#pragma unroll
            for (int j = 0; j < 4; ++j)
#pragma unroll
                for (int r = 0; r < 4; ++r)
                    C[(long)(m0 + wm + i * 16 + r0 + r) * ldc + (n0 + wn + j * 16 + col)] =
                        (TOUT)(acc[i][j][r] * scale);
    }
}

// ===== gemm_big256: R6 256x256, BK=32, triple-buffered 96KiB, 2-phase =====
// Counted vmcnt(4) (tile t+2 in flight across barrier), both-sides swizzle
// (linear gload_lds dest + lanes>=32 flip k by 16 on src + swizzled read).
// R6-proven at 519us total: used for V-proj, T-proj, and PV (long-K,N=1024).
template <typename TOUT, int MODE>
__global__ __launch_bounds__(512, 2) void gemm_big256(
    const bf16_t* __restrict__ A, int lda, long sAz,
    const bf16_t* __restrict__ B, int ldb, long sBz,
    TOUT* __restrict__ C, int ldc, long sCz,
    int K, float scale, float* __restrict__ l, long sLz)
{
    // [0,48K): A bufs x3 (16 KiB each)   [48K,96K): B bufs x3
    __shared__ __align__(1024) char smem[98304];

    A += (long)blockIdx.z * sAz;
    B += (long)blockIdx.z * sBz;
    C += (long)blockIdx.z * sCz;

    const int tid  = threadIdx.x;
    const int wave = tid >> 6;        // 0..7
    const int lane = tid & 63;
    const int m0 = blockIdx.x * 256;
    const int n0 = blockIdx.y * 256;
    const int wm = (wave >> 2) * 128; // 2 row-groups of 128
    const int wn = (wave & 3) * 64;   // 4 col-groups of 64

    // staging: linear LDS dest, pre-swizzled per-lane global source
    const int srow = wave * 16 + (lane >> 2);                       // 0..127
    const int skk  = ((lane & 3) * 8) ^ ((lane & 32) ? 16 : 0);     // elems
    const bf16_t* gA0 = A + (long)(m0 + srow) * lda + skk;
    const bf16_t* gA1 = A + (long)(m0 + srow + 128) * lda + skk;
    const bf16_t* gB0 = B + (long)(n0 + srow) * ldb + skk;
    const bf16_t* gB1 = B + (long)(n0 + srow + 128) * ldb + skk;
    char* ldsA = smem + wave * 1024;          // + buf*16384 (+8192 hi half)
    char* ldsB = smem + 49152 + wave * 1024;

    auto stage_A = [&](int kt, int d) {
        const int k0 = kt << 5;
        __builtin_amdgcn_global_load_lds((const gbl_void_t*)(gA0 + k0),
                                         (lds_void_t*)(ldsA + d * 16384), 16, 0, 0);
        __builtin_amdgcn_global_load_lds((const gbl_void_t*)(gA1 + k0),
                                         (lds_void_t*)(ldsA + d * 16384 + 8192), 16, 0, 0);
    };
    auto stage_B = [&](int kt, int d) {
        const int k0 = kt << 5;
        __builtin_amdgcn_global_load_lds((const gbl_void_t*)(gB0 + k0),
                                         (lds_void_t*)(ldsB + d * 16384), 16, 0, 0);
        __builtin_amdgcn_global_load_lds((const gbl_void_t*)(gB1 + k0),
                                         (lds_void_t*)(ldsB + d * 16384 + 8192), 16, 0, 0);
    };

    // ds_read: swizzled k-slot
    const int kswz = ((lane >> 4) * 16) ^ ((lane & 8) ? 32 : 0);
    const int aoff = (wm + (lane & 15)) * 64 + kswz;
    const int boff = (wn + (lane & 15)) * 64 + kswz;

    f32x4 acc[8][4];
#pragma unroll
    for (int i = 0; i < 8; ++i)
#pragma unroll
        for (int j = 0; j < 4; ++j)
            acc[i][j] = (f32x4){0.f, 0.f, 0.f, 0.f};

    const int NT = K >> 5;

    stage_A(0, 0); stage_B(0, 0);
    if (NT > 1) {
        stage_A(1, 1); stage_B(1, 1);
        asm volatile("s_waitcnt vmcnt(4)" ::: "memory");
    } else {
        asm volatile("s_waitcnt vmcnt(0)" ::: "memory");
    }
    __builtin_amdgcn_s_barrier();

    int cur = 0, nxt = 2;
    for (int t = 0; t < NT; ++t) {
        const char* pa = smem + cur * 16384 + aoff;
        const char* pb = smem + 49152 + cur * 16384 + boff;

        // phase 1: B frags + A rows [wm, wm+64), stage A(t+2)
        bf16x8 bfr[4], af[4];
#pragma unroll
        for (int j = 0; j < 4; ++j) bfr[j] = *(const bf16x8*)(pb + j * 1024);
#pragma unroll
        for (int i = 0; i < 4; ++i) af[i] = *(const bf16x8*)(pa + i * 1024);
        if (t + 2 < NT) stage_A(t + 2, nxt);
        __builtin_amdgcn_s_setprio(1);
#pragma unroll
        for (int i = 0; i < 4; ++i)
#pragma unroll
            for (int j = 0; j < 4; ++j)
                acc[i][j] = __builtin_amdgcn_mfma_f32_16x16x32_bf16(af[i], bfr[j], acc[i][j], 0, 0, 0);
        __builtin_amdgcn_s_setprio(0);

        // phase 2: A rows [wm+64, wm+128), stage B(t+2)
        bf16x8 af2[4];
#pragma unroll
        for (int i = 0; i < 4; ++i) af2[i] = *(const bf16x8*)(pa + 4096 + i * 1024);
        if (t + 2 < NT) stage_B(t + 2, nxt);
        __builtin_amdgcn_s_setprio(1);
#pragma unroll
        for (int i = 0; i < 4; ++i)
#pragma unroll
            for (int j = 0; j < 4; ++j)
                acc[4 + i][j] = __builtin_amdgcn_mfma_f32_16x16x32_bf16(af2[i], bfr[j], acc[4 + i][j], 0, 0, 0);
        __builtin_amdgcn_s_setprio(0);

        // boundary: counted vmcnt (tile t+1 landed, t+2 in flight)
        __builtin_amdgcn_sched_barrier(0);
        if (t + 2 < NT)
            asm volatile("s_waitcnt vmcnt(4) lgkmcnt(0)" ::: "memory");
        else if (t + 1 < NT)
            asm volatile("s_waitcnt vmcnt(0) lgkmcnt(0)" ::: "memory");
        else
            asm volatile("s_waitcnt lgkmcnt(0)" ::: "memory");
        __builtin_amdgcn_s_barrier();
        cur = (cur == 2) ? 0 : cur + 1;
        nxt = (nxt == 2) ? 0 : nxt + 1;
    }

    // ---- epilogue: C/D layout col = lane&15, row = (lane>>4)*4 + reg ----
    const int col = lane & 15;
    const int r0  = (lane >> 4) * 4;

    if (MODE == 1) {
#pragma unroll
        for (int i = 0; i < 8; ++i)
#pragma unroll
            for (int r = 0; r < 4; ++r) {
                float s = 0.f;
#pragma unroll
                for (int j = 0; j < 4; ++j) {
                    float e = __expf(acc[i][j][r] * scale);
                    acc[i][j][r] = e;
                    s += e;
                }
                s += __shfl_xor(s, 1);
                s += __shfl_xor(s, 2);
                s += __shfl_xor(s, 4);
                s += __shfl_xor(s, 8);
                if (col == 0)
                    atomicAdd(&l[(long)blockIdx.z * sLz + m0 + wm + i * 16 + r0 + r], s);
            }
#pragma unroll
        for (int i = 0; i < 8; ++i)
#pragma unroll
            for (int j = 0; j < 4; ++j)
#pragma unroll
                for (int r = 0; r < 4; ++r)
                    C[(long)(m0 + wm + i * 16 + r0 + r) * ldc + (n0 + wn + j * 16 + col)] =
                        (TOUT)acc[i][j][r];
    } else if (MODE == 2) {
        float inv[8][4];
#pragma unroll
        for (int i = 0; i < 8; ++i)
#pragma unroll
            for (int r = 0; r < 4; ++r)
                inv[i][r] = scale / l[(long)blockIdx.z * sLz + m0 + wm + i * 16 + r0 + r];
#pragma unroll
        for (int i = 0; i < 8; ++i)
#pragma unroll
            for (int j = 0; j < 4; ++j)
#pragma unroll
                for (int r = 0; r < 4; ++r)
                    C[(long)(m0 + wm + i * 16 + r0 + r) * ldc + (n0 + wn + j * 16 + col)] =
                        (TOUT)(acc[i][j][r] * inv[i][r]);
    } else {
#pragma unroll
        for (int i = 0; i < 8; ++i)
#pragma unroll
            for (int j = 0; j < 4; ++j)
#pragma unroll
                for (int r = 0; r < 4; ++r)
                    C[(long)(m0 + wm + i * 16 + r0 + r) * ldc + (n0 + wn + j * 16 + col)] =
                        (TOUT)(acc[i][j][r] * scale);
    }
}

// ===== score: 256x128 tile, BK=32, 8 waves, 3-buffered 72KiB LDS =====
// 2 blocks/CU, counted vmcnt(3), one barrier per K-tile, 2-way-max LDS
// swizzle (slot ^= (row>>1)&3 both-sides). Natural block order.
// Used ONLY for the short-K (1024) wide-N score GEMM (177us proven).
template <typename TOUT, int MODE, int LDA, int LDB, int LDC>
__global__ __launch_bounds__(512, 4) void gemm_bt256(
    const bf16_t* __restrict__ A, long sAz,
    const bf16_t* __restrict__ B, long sBz,
    TOUT* __restrict__ C, long sCz,
    int K, float scale, float* __restrict__ l, long sLz)
{
    __shared__ __align__(1024) char smem[73728];

    A += (long)blockIdx.z * sAz;
    B += (long)blockIdx.z * sBz;
    C += (long)blockIdx.z * sCz;

    const int m0 = blockIdx.x * 256;
    const int n0 = blockIdx.y * 128;

    const int tid  = threadIdx.x;
    const int wave = tid >> 6;        // 0..7
    const int lane = tid & 63;
    const int wm = (wave >> 2) * 128; // wave's 128-row slice of A-tile
    const int wn = (wave & 3) * 32;   // wave's 32-row slice of B-tile

    // staging source (per-lane, inverse-swizzled k slot)
    const int srow = wave * 16 + (lane >> 2);
    const int ksrc = (((lane & 3) ^ ((lane >> 3) & 3)) << 3);  // elems
    const bf16_t* pa0 = A + (long)(m0 + srow) * LDA + ksrc;
    const bf16_t* pa1 = pa0 + (long)128 * LDA;
    const bf16_t* pb0 = B + (long)(n0 + srow) * LDB + ksrc;
    const int ldsw = wave * 1024;

    // ds_read offsets (swizzled slot)
    const int kterm = (((lane >> 4) ^ ((lane >> 1) & 3)) << 4);  // bytes
    const int aoff = (wm + (lane & 15)) * 64 + kterm;
    const int boff = (wn + (lane & 15)) * 64 + kterm;

    f32x4 acc[8][2];
#pragma unroll
    for (int i = 0; i < 8; ++i)
#pragma unroll
        for (int j = 0; j < 2; ++j)
            acc[i][j] = (f32x4){0.f, 0.f, 0.f, 0.f};

    const int NT = K >> 5;

#define STAGE_A2(buf)                                                          \
    do {                                                                       \
        __builtin_amdgcn_global_load_lds((const gbl_void_t*)pa0,               \
            (lds_void_t*)(smem + (buf)*16384 + ldsw), 16, 0, 0);               \
        __builtin_amdgcn_global_load_lds((const gbl_void_t*)pa1,               \
            (lds_void_t*)(smem + (buf)*16384 + 8192 + ldsw), 16, 0, 0);        \
    } while (0)
#define STAGE_B1(buf)                                                          \
    __builtin_amdgcn_global_load_lds((const gbl_void_t*)pb0,                   \
        (lds_void_t*)(smem + 49152 + (buf)*8192 + ldsw), 16, 0, 0)

    // prologue: stage tiles 0 and 1; wait tile 0 (leave tile 1 in flight)
    STAGE_A2(0); STAGE_B1(0); pa0 += 32; pa1 += 32; pb0 += 32;
    if (NT > 1) {
        STAGE_A2(1); STAGE_B1(1); pa0 += 32; pa1 += 32; pb0 += 32;
        asm volatile("s_waitcnt vmcnt(3)" ::: "memory");
    } else {
        asm volatile("s_waitcnt vmcnt(0)" ::: "memory");
    }
    __builtin_amdgcn_sched_barrier(0);
    __builtin_amdgcn_s_barrier();

    int cur = 0, sb = 2;
    for (int t = 0; t < NT; ++t) {
        const char* Ab = smem + cur * 16384;
        const char* Bb = smem + 49152 + cur * 8192;
        const bool more = (t + 2 < NT);

        bf16x8 bfr[2], af[4];
#pragma unroll
        for (int j = 0; j < 2; ++j) bfr[j] = *(const bf16x8*)(Bb + boff + j * 1024);
#pragma unroll
        for (int i = 0; i < 4; ++i) af[i] = *(const bf16x8*)(Ab + aoff + i * 1024);
        if (more) STAGE_A2(sb);
        asm volatile("s_waitcnt lgkmcnt(0)" ::: "memory");
        __builtin_amdgcn_sched_barrier(0);
        __builtin_amdgcn_s_setprio(1);
#pragma unroll
        for (int i = 0; i < 4; ++i)
#pragma unroll
            for (int j = 0; j < 2; ++j)
                acc[i][j] = __builtin_amdgcn_mfma_f32_16x16x32_bf16(af[i], bfr[j], acc[i][j], 0, 0, 0);
        __builtin_amdgcn_s_setprio(0);

#pragma unroll
        for (int i = 0; i < 4; ++i) af[i] = *(const bf16x8*)(Ab + aoff + 4096 + i * 1024);
        if (more) STAGE_B1(sb);
        asm volatile("s_waitcnt lgkmcnt(0)" ::: "memory");
        __builtin_amdgcn_sched_barrier(0);
        __builtin_amdgcn_s_setprio(1);
#pragma unroll
        for (int i = 0; i < 4; ++i)
#pragma unroll
            for (int j = 0; j < 2; ++j)
                acc[4 + i][j] = __builtin_amdgcn_mfma_f32_16x16x32_bf16(af[i], bfr[j], acc[4 + i][j], 0, 0, 0);
        __builtin_amdgcn_s_setprio(0);

        // boundary: retire tile t+1's loads; keep tile t+2's in flight
        if (more) {
            asm volatile("s_waitcnt vmcnt(3)" ::: "memory");
            pa0 += 32; pa1 += 32; pb0 += 32;
        } else if (t + 1 < NT) {
            asm volatile("s_waitcnt vmcnt(0)" ::: "memory");
        }
        __builtin_amdgcn_sched_barrier(0);
        __builtin_amdgcn_s_barrier();
        cur = (cur == 2) ? 0 : cur + 1;
        sb  = (sb == 2) ? 0 : sb + 1;
    }
#undef STAGE_A2
#undef STAGE_B1

    // ---- epilogue: C/D layout col = lane&15, row = (lane>>4)*4 + reg ----
    const int col = lane & 15;
    const int r0  = (lane >> 4) * 4;

    if (MODE == 1) {
#pragma unroll
        for (int i = 0; i < 8; ++i)
#pragma unroll
            for (int r = 0; r < 4; ++r) {
                float s = 0.f;
#pragma unroll
                for (int j = 0; j < 2; ++j) {
                    float e = __expf(acc[i][j][r] * scale);
                    acc[i][j][r] = e;
                    s += e;
                }
                s += __shfl_xor(s, 1);
                s += __shfl_xor(s, 2);
                s += __shfl_xor(s, 4);
                s += __shfl_xor(s, 8);
                if (col == 0)
                    atomicAdd(&l[(long)blockIdx.z * sLz + m0 + wm + i * 16 + r0 + r], s);
            }
#pragma unroll
        for (int i = 0; i < 8; ++i)
#pragma unroll
            for (int j = 0; j < 2; ++j)
#pragma unroll
                for (int r = 0; r < 4; ++r)
                    C[(long)(m0 + wm + i * 16 + r0 + r) * LDC + (n0 + wn + j * 16 + col)] =
                        (TOUT)acc[i][j][r];
    } else if (MODE == 2) {
        float inv[8][4];
#pragma unroll
        for (int i = 0; i < 8; ++i)
#pragma unroll
            for (int r = 0; r < 4; ++r)
                inv[i][r] = scale / l[(long)blockIdx.z * sLz + m0 + wm + i * 16 + r0 + r];
#pragma unroll
        for (int i = 0; i < 8; ++i)
#pragma unroll
            for (int j = 0; j < 2; ++j)
#pragma unroll
                for (int r = 0; r < 4; ++r)
                    C[(long)(m0 + wm + i * 16 + r0 + r) * LDC + (n0 + wn + j * 16 + col)] =
                        (TOUT)(acc[i][j][r] * inv[i][r]);
    } else {
#pragma unroll
        for (int i = 0; i < 8; ++i)
#pragma unroll
            for (int j = 0; j < 2; ++j)
#pragma unroll
                for (int r = 0; r < 4; ++r)
                    C[(long)(m0 + wm + i * 16 + r0 + r) * LDC + (n0 + wn + j * 16 + col)] =
                        (TOUT)(acc[i][j][r] * scale);
    }
}

// ---------------- row softmax (fallback path only) ----------------
__device__ __forceinline__ float waveMax(float v)
{
#pragma unroll
    for (int o = 32; o > 0; o >>= 1) v = fmaxf(v, __shfl_xor(v, o));
    return v;
}
__device__ __forceinline__ float waveSum(float v)
{
#pragma unroll
    for (int o = 32; o > 0; o >>= 1) v += __shfl_xor(v, o);
    return v;
}

__global__ __launch_bounds__(256) void softmax_rows(bf16_t* __restrict__ S)
{
    const long row = blockIdx.x;
    bf16_t* p = S + row * SEQ;
    const int tid = threadIdx.x;

    float v[16];
    bf16x8 a0 = *(const bf16x8*)(p + tid * 16);
    bf16x8 a1 = *(const bf16x8*)(p + tid * 16 + 8);
#pragma unroll
    for (int i = 0; i < 8; ++i) { v[i] = (float)a0[i]; v[8 + i] = (float)a1[i]; }

    float m = -1e30f;
#pragma unroll
    for (int i = 0; i < 16; ++i) m = fmaxf(m, v[i]);

    __shared__ float redm[4];
    __shared__ float reds[4];
    m = waveMax(m);
    if ((tid & 63) == 0) redm[tid >> 6] = m;
    __syncthreads();
    m = fmaxf(fmaxf(redm[0], redm[1]), fmaxf(redm[2], redm[3]));

    float s = 0.f;
#pragma unroll
    for (int i = 0; i < 16; ++i) { v[i] = __expf(v[i] - m); s += v[i]; }
    s = waveSum(s);
    if ((tid & 63) == 0) reds[tid >> 6] = s;
    __syncthreads();
    s = reds[0] + reds[1] + reds[2] + reds[3];
    const float inv = 1.0f / s;

    bf16x8 o0, o1;
#pragma unroll
    for (int i = 0; i < 8; ++i) {
        o0[i] = (bf16_t)(v[i] * inv);
        o1[i] = (bf16_t)(v[8 + i] * inv);
    }
    *(bf16x8*)(p + tid * 16)     = o0;
    *(bf16x8*)(p + tid * 16 + 8) = o1;
}

// ------- bf16 tile transpose (z-batched): out[z][x][y] = in[z][y][x] -------
__global__ __launch_bounds__(256) void transpose_bf16(
    const bf16_t* __restrict__ in, int ldin, long sInZ,
    bf16_t* __restrict__ out, int ldout, long sOutZ)
{
    in  += (long)blockIdx.z * sInZ;
    out += (long)blockIdx.z * sOutZ;
    __shared__ bf16_t t[32][33];
    const int tx = threadIdx.x;  // 0..31
    const int ty = threadIdx.y;  // 0..7
    const int x  = blockIdx.x * 32 + tx;
    const int y0 = blockIdx.y * 32;
#pragma unroll
    for (int i = 0; i < 4; ++i)
        t[ty + i * 8][tx] = in[(long)(y0 + ty + i * 8) * ldin + x];
    __syncthreads();
    const int xo = blockIdx.x * 32;
#pragma unroll
    for (int i = 0; i < 4; ++i)
        out[(long)(xo + ty + i * 8) * ldout + y0 + tx] = t[tx][ty + i * 8];
}

// ---------------- launcher ----------------
extern "C" void kernel_launch(void* const* d_in, const int* in_sizes, int n_in,
                              void* d_out, int out_size, void* d_ws, size_t ws_size,
                              hipStream_t stream)
{
    const float* X  = (const float*)d_in[0];  // (4,4096,1024)
    const float* Wq = (const float*)d_in[1];  // (1024,1024)
    const float* Wk = (const float*)d_in[2];
    const float* Wv = (const float*)d_in[3];
    float* out = (float*)d_out;               // (4,4096,1024) fp32
    char* ws = (char*)d_ws;

    if (ws_size >= (256ull << 20)) {
        // ===== batched fused path (<=237 MiB used) =====
        // [0,32M)     Xbf (alive until score GEMM)
        // [32,64M)    Vbf, then reused as Tbuf (V dead after transpose)
        // [64,96M)    VT x4 (bf16 1024x4096 each)
        // [96,224M)   S0..S3 (bf16 4096x4096 each, = exp(scores))
        // [224,230M)  Wall = bf16 [Wq;Wk;Wv]
        // [230,232M)  WqT   [232,234M) WkT   [234,236M) Mt = Wk^T Wq
        // [236M,+64K) l (fp32 16384)
        bf16_t* Xbf  = (bf16_t*)ws;
        bf16_t* Vbf  = (bf16_t*)(ws + (32l << 20));
        bf16_t* Tbuf = (bf16_t*)(ws + (32l << 20));   // reuses Vbf after transV
        bf16_t* VT   = (bf16_t*)(ws + (64l << 20));
        bf16_t* Sbuf = (bf16_t*)(ws + (96l << 20));
        bf16_t* Wall = (bf16_t*)(ws + (224l << 20));
        bf16_t* WqT  = (bf16_t*)(ws + (230l << 20));
        bf16_t* WkT  = (bf16_t*)(ws + (232l << 20));
        bf16_t* Mt   = (bf16_t*)(ws + (234l << 20));
        float*  lbuf = (float*)(ws + (236l << 20));

        cast_f32_to_bf16<<<(16777216 / 8) / 256, 256, 0, stream>>>(X, Xbf, 16777216 / 8);
        cast3_w<<<dim3(512, 1, 3), 256, 0, stream>>>(Wq, Wk, Wv, Wall);

        transpose_bf16<<<dim3(32, 32, 2), dim3(32, 8), 0, stream>>>(
            Wall, DM, 1048576, WqT, DM, 1048576);

        // Mt = Wk^T Wq, 1024x1024 (small; 128-tile path)
        gemm_bt<bf16_t, 0><<<dim3(8, 8, 1), 256, 0, stream>>>(
            WkT, DM, 0l, WqT, DM, 0l, Mt, DM, 0l, DM, 1.0f, nullptr, 0l);

        // V = X @ Wv^T : M=16384, N=1024, K=1024 (256^2 kernel, R6-proven)
        gemm_big256<bf16_t, 0><<<dim3(64, 4, 1), 512, 0, stream>>>(
            Xbf, DM, 0l, Wall + 2097152, DM, 0l, Vbf, DM, 0l, DM, 1.0f, nullptr, 0l);

        // VT[b][d][s] = V[b][s][d]
        transpose_bf16<<<dim3(DM / 32, SEQ / 32, 4), dim3(32, 8), 0, stream>>>(
            Vbf, DM, (long)SEQ * DM, VT, SEQ, (long)DM * SEQ);

        // T = X @ Mt^T : replaces BOTH Q and K projections (into dead Vbf)
        gemm_big256<bf16_t, 0><<<dim3(64, 4, 1), 512, 0, stream>>>(
            Xbf, DM, 0l, Mt, DM, 0l, Tbuf, DM, 0l, DM, 1.0f, nullptr, 0l);

        zero_f32<<<64, 256, 0, stream>>>(lbuf, 4 * SEQ);

        // P[b] = exp(T[b] X[b]^T / 32): 256x128 kernel (short K, wide N)
        gemm_bt256<bf16_t, 1, DM, DM, SEQ><<<dim3(16, 32, 4), 512, 0, stream>>>(
            Tbuf, (long)SEQ * DM,
            Xbf, (long)SEQ * DM,
            Sbuf, (long)SEQ * SEQ, DM, 0.03125f, lbuf, SEQ);

        // O[b] = (P[b] @ V[b]) / l : 256^2 kernel (long K, narrow N)
        gemm_big256<float, 2><<<dim3(16, 4, 4), 512, 0, stream>>>(
            Sbuf, SEQ, (long)SEQ * SEQ,
            VT, SEQ, (long)DM * SEQ,
            out, DM, (long)SEQ * DM, SEQ, 1.0f, lbuf, SEQ);
    } else {
        // ===== fallback: per-batch path (<=145 MiB ws, proven) =====
        bf16_t* Sbuf = (bf16_t*)ws;
        bf16_t* Xbf  = (bf16_t*)ws;
        bf16_t* Wall = (bf16_t*)(ws + (33l << 20));
        bf16_t* QKV  = (bf16_t*)(ws + (40l << 20));
        bf16_t* VT   = (bf16_t*)(ws + (137l << 20));

        cast_f32_to_bf16<<<(16777216 / 8) / 256, 256, 0, stream>>>(X, Xbf, 16777216 / 8);
        cast3_w<<<dim3(512, 1, 3), 256, 0, stream>>>(Wq, Wk, Wv, Wall);

        gemm_bt<bf16_t, 0><<<dim3(128, 24, 1), 256, 0, stream>>>(
            Xbf, DM, 0l, Wall, DM, 0l, QKV, 3072, 0l, DM, 1.0f, nullptr, 0l);

        for (int b = 0; b < 4; ++b) {
            const bf16_t* Qb = QKV + (long)b * SEQ * 3072;
            gemm_bt<bf16_t, 0><<<dim3(32, 32, 1), 256, 0, stream>>>(
                Qb, 3072, 0l, Qb + 1024, 3072, 0l, Sbuf, SEQ, 0l, DM, 0.03125f, nullptr, 0l);
            softmax_rows<<<SEQ, 256, 0, stream>>>(Sbuf);
            transpose_bf16<<<dim3(DM / 32, SEQ / 32, 1), dim3(32, 8), 0, stream>>>(
                Qb + 2048, 3072, 0l, VT, SEQ, 0l);
            gemm_bt<float, 0><<<dim3(32, 8, 1), 256, 0, stream>>>(
                Sbuf, SEQ, 0l, VT, SEQ, 0l, out + (long)b * SEQ * DM, DM, 0l, SEQ, 1.0f, nullptr, 0l);
        }
    }
}